// Round 9
// baseline (176.698 us; speedup 1.0000x reference)
//
#include <hip/hip_runtime.h>

// Paged attention decode, GQA: B=32, H=32, KVH=8 (G=4), D=128, pages of 16.
// R9: deep async pipeline. Block = (b, part=64 tok); 256 threads span the full
// 4KB token row (page read once, contiguously). K/V staged into WAVE-PRIVATE
// LDS slabs via __builtin_amdgcn_global_load_lds (16B/lane, linear dst, no
// barriers, no VGPR buffering). Chunk = 2 tokens = 4 gld_lds per wave;
// DEPTH=3 ring; counted s_waitcnt vmcnt(8) keeps 2 chunks (8KB/wave) in
// flight through compute -- never drained to 0 inside the loop (T3/T4).
// 48KB LDS -> 3 blocks/CU = 12 waves/CU. Dynamic unit queue (R8).

constexpr int Dh   = 128;
constexpr int Gq   = 4;
constexpr int KVH  = 8;
constexpr int Hq   = 32;
constexpr int Bb   = 32;
constexpr int MB   = 256;
constexpr int PAGE = 16;
constexpr float SCALE = 0.08838834764831845f;

constexpr int NPARTS      = 64;
constexpr int PART_TOKENS = 64;                  // 4 pages per part
constexpr int PG_FLOATS   = PAGE * KVH * Dh;     // 16384 floats = 64 KB
constexpr int ROW_FLOATS  = KVH * Dh;            // 1024 floats per token row
constexpr int NUNITS      = Bb * NPARTS;         // 2048

// per-(b,part) workspace floats: acc[32 heads][128] + m[32] + l[32]
constexpr int PART_STRIDE = Hq * Dh + 2 * Hq;    // 4160

constexpr size_t CTR_BYTE_OFF = (size_t)128 << 20;   // partials end ~34 MB

__global__ void init_ctr(int* ctr) { *ctr = 0; }

__device__ __forceinline__ void gld16(const float* g, float* l) {
    __builtin_amdgcn_global_load_lds(
        (const __attribute__((address_space(1))) void*)g,
        (__attribute__((address_space(3))) void*)l, 16, 0, 0);
}

__global__ __launch_bounds__(256, 3)
void attn_partial(const float* __restrict__ q,
                  const float* __restrict__ kc,
                  const float* __restrict__ vc,
                  const int*   __restrict__ bt,
                  const int*   __restrict__ cl,
                  float*       __restrict__ ws,
                  int*         __restrict__ ctr)
{
    const int t      = threadIdx.x;              // 0..255
    const int wave   = t >> 6;
    const int lane   = t & 63;
    const int kvh    = t >> 5;
    const int lane32 = t & 31;
    const int doff   = lane32 * 4;

    // [wave][depth=3][tok-in-chunk=2][K/V=2][256 floats]  = 48 KB, wave-private
    __shared__ float slab[4][3][2][2][256];
    __shared__ int s_unit;

    float* const myslab = &slab[wave][0][0][0][0];
    const int lane4 = lane * 4;
    const int t4    = t * 4;                     // float offset within a 4KB row

    for (;;) {
        if (t == 0) s_unit = atomicAdd(ctr, 1);
        __syncthreads();
        const int unit = s_unit;
        __syncthreads();
        if (unit >= NUNITS) break;

        const int b    = unit & (Bb - 1);        // part-major order (LPT-ish)
        const int part = unit >> 5;

        const int ctx    = cl[b];
        const int pstart = part * PART_TOKENS;
        if (pstart >= ctx) continue;
        const int n  = min(PART_TOKENS, ctx - pstart);
        const int TC = (n + 1) >> 1;             // 2-token chunks, 1..32

        const int4 pg = *(const int4*)(bt + b * MB + (pstart >> 4));

        // Q fragments, pre-scaled: head (kvh,g), dims [doff, doff+4)
        float4 qv[Gq];
        {
            const float* qbase = q + (size_t)(b * Hq + kvh * Gq) * Dh + doff;
            #pragma unroll
            for (int g = 0; g < Gq; ++g) {
                float4 x = *(const float4*)(qbase + g * Dh);
                qv[g] = make_float4(x.x * SCALE, x.y * SCALE, x.z * SCALE, x.w * SCALE);
            }
        }

        float4 acc[Gq];
        float  m_run[Gq], l_run[Gq];
        #pragma unroll
        for (int g = 0; g < Gq; ++g) {
            acc[g] = make_float4(0.f, 0.f, 0.f, 0.f);
            m_run[g] = -1e30f;
            l_run[g] = 0.f;
        }

        auto physof = [&](int pgi) -> int {
            return pgi == 0 ? pg.x : (pgi == 1 ? pg.y : (pgi == 2 ? pg.z : pg.w));
        };

        // stage chunk c (tokens 2c, 2c+1): 4 x gld_lds of 1KB per wave
        auto STAGE = [&](int c) {
            const int buf = c % 3;
            float* dst = myslab + buf * 1024;
            #pragma unroll
            for (int tp = 0; tp < 2; ++tp) {
                const int tok  = c * 2 + tp;
                const int phys = physof(tok >> 4);
                const size_t roff = (size_t)phys * PG_FLOATS
                                  + (size_t)(tok & 15) * ROW_FLOATS + t4;
                gld16(kc + roff, dst + tp * 512);
                gld16(vc + roff, dst + tp * 512 + 256);
            }
        };

        auto COMPUTE = [&](int c) {
            const int buf = c % 3;
            const float* sb = myslab + buf * 1024;
            const float4 k0 = *(const float4*)(sb +       lane4);
            const float4 v0 = *(const float4*)(sb + 256 + lane4);
            const float4 k1 = *(const float4*)(sb + 512 + lane4);
            const float4 v1 = *(const float4*)(sb + 768 + lane4);
            const bool ok1 = (c * 2 + 1) < n;    // token 2c is always valid
            float s0[Gq], s1[Gq];
            #pragma unroll
            for (int g = 0; g < Gq; ++g) {
                float d0 = k0.x*qv[g].x + k0.y*qv[g].y + k0.z*qv[g].z + k0.w*qv[g].w;
                float d1 = k1.x*qv[g].x + k1.y*qv[g].y + k1.z*qv[g].z + k1.w*qv[g].w;
                d0 += __shfl_xor(d0, 1);  d1 += __shfl_xor(d1, 1);
                d0 += __shfl_xor(d0, 2);  d1 += __shfl_xor(d1, 2);
                d0 += __shfl_xor(d0, 4);  d1 += __shfl_xor(d1, 4);
                d0 += __shfl_xor(d0, 8);  d1 += __shfl_xor(d1, 8);
                d0 += __shfl_xor(d0, 16); d1 += __shfl_xor(d1, 16);
                s0[g] = d0;
                s1[g] = ok1 ? d1 : -1e30f;
            }
            #pragma unroll
            for (int g = 0; g < Gq; ++g) {
                const float tm    = fmaxf(s0[g], s1[g]);
                const float mn    = fmaxf(m_run[g], tm);
                const float alpha = __expf(m_run[g] - mn);
                m_run[g] = mn;
                const float p0 = __expf(s0[g] - mn);
                const float p1 = __expf(s1[g] - mn);
                l_run[g] = l_run[g] * alpha + (p0 + p1);
                acc[g].x = fmaf(p1, v1.x, fmaf(p0, v0.x, acc[g].x * alpha));
                acc[g].y = fmaf(p1, v1.y, fmaf(p0, v0.y, acc[g].y * alpha));
                acc[g].z = fmaf(p1, v1.z, fmaf(p0, v0.z, acc[g].z * alpha));
                acc[g].w = fmaf(p1, v1.w, fmaf(p0, v0.w, acc[g].w * alpha));
            }
        };

        // ---- deep pipeline: 3-deep ring, counted vmcnt, never drain in loop ----
        STAGE(0);
        if (TC > 1) STAGE(1);
        int c = 0;
        for (; c + 2 < TC; ++c) {
            STAGE(c + 2);                        // up to 12 outstanding
            asm volatile("s_waitcnt vmcnt(8)" ::: "memory");   // chunk c landed
            COMPUTE(c);
        }
        if (c + 1 < TC) {                        // TC >= 2 tail: one stage in flight
            asm volatile("s_waitcnt vmcnt(4)" ::: "memory");
            COMPUTE(c);
            ++c;
        }
        asm volatile("s_waitcnt vmcnt(0)" ::: "memory");
        COMPUTE(c);                              // c == TC-1

        // ---- write partials: head (kvh,g), dims [doff, doff+4) ----
        float* wp = ws + (size_t)(b * NPARTS + part) * PART_STRIDE;
        #pragma unroll
        for (int g = 0; g < Gq; ++g)
            *(float4*)(wp + (kvh * Gq + g) * Dh + doff) = acc[g];
        if (lane32 == 0) {
            #pragma unroll
            for (int g = 0; g < Gq; ++g) {
                wp[Hq * Dh + kvh * Gq + g]      = m_run[g];
                wp[Hq * Dh + Hq + kvh * Gq + g] = l_run[g];
            }
        }
    }
}

__global__ __launch_bounds__(256, 4)
void attn_reduce(const float* __restrict__ ws,
                 const int*   __restrict__ cl,
                 float*       __restrict__ out)
{
    const int b       = blockIdx.x >> 2;
    const int quarter = blockIdx.x & 3;
    const int tid     = threadIdx.x;
    const int h       = quarter * 8 + (tid >> 5);
    const int doff    = (tid & 31) * 4;

    const int ctx = cl[b];
    const int np  = min(NPARTS, (ctx + PART_TOKENS - 1) / PART_TOKENS);

    const float* base = ws + (size_t)b * NPARTS * PART_STRIDE;

    float m = -1e30f;
    for (int p = 0; p < np; ++p)
        m = fmaxf(m, base[p * PART_STRIDE + Hq * Dh + h]);

    float L = 0.f;
    float ax = 0.f, ay = 0.f, az = 0.f, aw = 0.f;
    for (int p = 0; p < np; ++p) {
        const float* bp = base + p * PART_STRIDE;
        const float c = __expf(bp[Hq * Dh + h] - m);
        L += bp[Hq * Dh + Hq + h] * c;
        const float4 v = *(const float4*)(bp + h * Dh + doff);
        ax = fmaf(c, v.x, ax);
        ay = fmaf(c, v.y, ay);
        az = fmaf(c, v.z, az);
        aw = fmaf(c, v.w, aw);
    }
    const float inv = 1.f / L;
    float* op = out + (size_t)(b * Hq + h) * Dh + doff;
    *(float4*)op = make_float4(ax * inv, ay * inv, az * inv, aw * inv);
}

extern "C" void kernel_launch(void* const* d_in, const int* in_sizes, int n_in,
                              void* d_out, int out_size, void* d_ws, size_t ws_size,
                              hipStream_t stream) {
    const float* q  = (const float*)d_in[0];
    const float* kc = (const float*)d_in[1];
    const float* vc = (const float*)d_in[2];
    const int*   bt = (const int*)d_in[3];
    const int*   cl = (const int*)d_in[4];
    float* out = (float*)d_out;
    float* ws  = (float*)d_ws;
    int*   ctr = (int*)((char*)d_ws + CTR_BYTE_OFF);

    init_ctr<<<dim3(1), dim3(1), 0, stream>>>(ctr);
    attn_partial<<<dim3(768), dim3(256), 0, stream>>>(q, kc, vc, bt, cl, ws, ctr);
    attn_reduce<<<dim3(Bb * 4), dim3(256), 0, stream>>>(ws, cl, out);
}